// Round 16
// baseline (324.399 us; speedup 1.0000x reference)
//
#include <hip/hip_runtime.h>
#include <hip/hip_bf16.h>

#define MM 2048     // memory slots
#define BB 64       // batch
#define TT 4        // tokens per slot
#define DD 128      // embed dim
#define VV 50000    // vocab
#define VPAD 50176  // VV rounded up to multiple of 256
#define NPART 392   // gemm_o partial slots (one per block)
#define NATT 2048   // attn blocks = per-m Zp partial slots

typedef float f4v __attribute__((ext_vector_type(4)));
typedef short s8v __attribute__((ext_vector_type(8)));

// float -> bf16 bits (RNE) via compiler codegen (m240: beats hand-written asm;
// clang fuses adjacent pairs into v_cvt_pk_bf16_f32)
__device__ __forceinline__ unsigned short f2bf(float f) {
    return __builtin_bit_cast(unsigned short, __float2bfloat16(f));
}
// bf16 bits -> float
__device__ __forceinline__ float bf2f(unsigned short s) {
    return __uint_as_float((unsigned)s << 16);
}
// pack two floats as bf16 pair (lo -> bits 0..15, hi -> bits 16..31)
__device__ __forceinline__ unsigned pk2(float lo, float hi) {
    return ((unsigned)f2bf(hi) << 16) | f2bf(lo);
}

// ---- init: zero u (8192 f) and W (VPAD*BB f) — contiguous in workspace ----
__global__ void k_init(float4* __restrict__ p) {
    p[blockIdx.x * 256 + threadIdx.x] = make_float4(0.f, 0.f, 0.f, 0.f);
}

// ---- hop 0 scatter, token-parallel: W[tok][b] += 1/2048 (prob exact) ----
__global__ __launch_bounds__(256) void k_scatter0(const int* __restrict__ st,
                                                  float* __restrict__ W) {
    const int g4 = blockIdx.x * 256 + threadIdx.x;   // token index
    const int b = (g4 >> 2) & 63;
    const int tok = st[g4];                          // coalesced
    if (tok) atomicAdd(W + (size_t)tok * 64 + b, 1.0f / (float)MM);
}

// ---- GEMM1 (MFMA bf16): P16[v][b] = bf16(dot(C[h][v][:], u[b][:])) ----
// 128 v-rows per block. LDS rows 0..127 = C tile, 128..191 = u.
__global__ __launch_bounds__(256, 3) void k_gemm_p(const float* __restrict__ Ch,
                                                   const float* __restrict__ u,
                                                   unsigned short* __restrict__ P16) {
    __shared__ short lds[192 * 136];  // 52.2 KB bf16 -> 3 blocks/CU
    const int t = threadIdx.x;
    const int v0 = blockIdx.x * 128;

#pragma unroll
    for (int i = 0; i < 24; ++i) {
        const int G = i * 256 + t;        // f4-index, 6144 total
        const int row = G >> 5;           // 0..191
        const int c4 = G & 31;
        float4 val;
        if (row < 128) {
            const int v = v0 + row;
            val = (v < VV) ? *(const float4*)(Ch + (size_t)v * DD + c4 * 4)
                           : make_float4(0.f, 0.f, 0.f, 0.f);
        } else {
            val = *(const float4*)(u + (size_t)(row - 128) * DD + c4 * 4);
        }
        const unsigned lo = pk2(val.x, val.y);
        const unsigned hi = pk2(val.z, val.w);
        *(uint2*)(lds + row * 136 + c4 * 4) = make_uint2(lo, hi);
    }
    __syncthreads();

    const int l = t & 63;
    const int w = t >> 6;
    const int quad = l >> 4;
    const int n16 = l & 15;

    const int ar0 = (32 * w + n16) * 136;
    const int ar1 = (32 * w + 16 + n16) * 136;
    const int br0 = (128 + n16) * 136;
    const int br1 = (144 + n16) * 136;
    const int br2 = (160 + n16) * 136;
    const int br3 = (176 + n16) * 136;

    f4v c00 = {0.f, 0.f, 0.f, 0.f}, c01 = c00, c02 = c00, c03 = c00;
    f4v c10 = c00, c11 = c00, c12 = c00, c13 = c00;

#pragma unroll
    for (int s = 0; s < 4; ++s) {
        const int ko = s * 32 + quad * 8;
        const s8v a0 = *(const s8v*)(lds + ar0 + ko);
        const s8v a1 = *(const s8v*)(lds + ar1 + ko);
        const s8v b0 = *(const s8v*)(lds + br0 + ko);
        const s8v b1 = *(const s8v*)(lds + br1 + ko);
        const s8v b2 = *(const s8v*)(lds + br2 + ko);
        const s8v b3 = *(const s8v*)(lds + br3 + ko);
        c00 = __builtin_amdgcn_mfma_f32_16x16x32_bf16(a0, b0, c00, 0, 0, 0);
        c01 = __builtin_amdgcn_mfma_f32_16x16x32_bf16(a0, b1, c01, 0, 0, 0);
        c02 = __builtin_amdgcn_mfma_f32_16x16x32_bf16(a0, b2, c02, 0, 0, 0);
        c03 = __builtin_amdgcn_mfma_f32_16x16x32_bf16(a0, b3, c03, 0, 0, 0);
        c10 = __builtin_amdgcn_mfma_f32_16x16x32_bf16(a1, b0, c10, 0, 0, 0);
        c11 = __builtin_amdgcn_mfma_f32_16x16x32_bf16(a1, b1, c11, 0, 0, 0);
        c12 = __builtin_amdgcn_mfma_f32_16x16x32_bf16(a1, b2, c12, 0, 0, 0);
        c13 = __builtin_amdgcn_mfma_f32_16x16x32_bf16(a1, b3, c13, 0, 0, 0);
    }

    const int vb0 = v0 + 32 * w + quad * 4;
    const int vb1 = vb0 + 16;
#pragma unroll
    for (int r = 0; r < 4; ++r) {
        unsigned short* __restrict__ P0 = P16 + (size_t)(vb0 + r) * 64 + n16;
        P0[0]  = f2bf(c00[r]); P0[16] = f2bf(c01[r]);
        P0[32] = f2bf(c02[r]); P0[48] = f2bf(c03[r]);
        unsigned short* __restrict__ P1 = P16 + (size_t)(vb1 + r) * 64 + n16;
        P1[0]  = f2bf(c10[r]); P1[16] = f2bf(c11[r]);
        P1[32] = f2bf(c12[r]); P1[48] = f2bf(c13[r]);
    }
}

// ---- attention, token-parallel: one thread per (m,b,t), quad-shuffle score ----
__global__ __launch_bounds__(256) void k_attn2(const int* __restrict__ st,
                                               const unsigned short* __restrict__ P16,
                                               float* __restrict__ W,
                                               float* __restrict__ Zp) {
    __shared__ float eb[64];
    const int tid = threadIdx.x;
    const int g4 = blockIdx.x * 256 + tid;   // token index; mb = g4>>2
    const int b = (g4 >> 2) & 63;            // = tid>>2

    const int tok = st[g4];                  // coalesced scalar load
    float v = 0.f;
    if (tok) v = bf2f(P16[(size_t)tok * 64 + b]);
    v += __shfl_xor(v, 1, 64);
    v += __shfl_xor(v, 2, 64);
    const float e = __expf(v);

    if (tok) atomicAdd(W + (size_t)tok * 64 + b, e);

    if ((tid & 3) == 0) eb[tid >> 2] = e;    // quad leader; eb index == b
    __syncthreads();
    if (tid < 64) Zp[(size_t)blockIdx.x * 64 + tid] = eb[tid];
}

// ---- GEMM2 (MFMA bf16): partials PACKED bf16x2 -> upk[part][b][wi] ----
// word wi = w*16+n16 holds (d0, d0+16) where d0 = (wi>>4)*32 + (wi&15).
__global__ __launch_bounds__(256, 3) void k_gemm_o(const float* __restrict__ C2,
                                                   float* __restrict__ W,
                                                   unsigned* __restrict__ upk,
                                                   const int rezero) {
    __shared__ unsigned Wt[64 * 68];    // 17.4 KB [b][v-pair]
    __shared__ unsigned Ct[128 * 68];   // 34.8 KB [d][v-pair]
    const int t = threadIdx.x;
    const int vb = blockIdx.x * 128;

#pragma unroll
    for (int i = 0; i < 4; ++i) {
        const int item = i * 256 + t;
        const int q = item & 15;          // b-quad
        const int p = item >> 4;          // v-pair 0..63
        float* w0 = W + (size_t)(vb + 2 * p) * 64 + 4 * q;
        float* w1 = W + (size_t)(vb + 2 * p + 1) * 64 + 4 * q;
        const float4 x = *(const float4*)w0;
        const float4 y = *(const float4*)w1;
        if (rezero) {
            *(float4*)w0 = make_float4(0.f, 0.f, 0.f, 0.f);
            *(float4*)w1 = make_float4(0.f, 0.f, 0.f, 0.f);
        }
        Wt[(4 * q + 0) * 68 + p] = pk2(x.x, y.x);
        Wt[(4 * q + 1) * 68 + p] = pk2(x.y, y.y);
        Wt[(4 * q + 2) * 68 + p] = pk2(x.z, y.z);
        Wt[(4 * q + 3) * 68 + p] = pk2(x.w, y.w);
    }
#pragma unroll
    for (int i = 0; i < 8; ++i) {
        const int item = i * 256 + t;
        const int q = item & 31;          // d-quad
        const int p = item >> 5;          // v-pair 0..63
        const int v0 = vb + 2 * p;
        const float4 x = (v0 < VV)
            ? *(const float4*)(C2 + (size_t)v0 * DD + 4 * q)
            : make_float4(0.f, 0.f, 0.f, 0.f);
        const float4 y = (v0 + 1 < VV)
            ? *(const float4*)(C2 + (size_t)(v0 + 1) * DD + 4 * q)
            : make_float4(0.f, 0.f, 0.f, 0.f);
        Ct[(4 * q + 0) * 68 + p] = pk2(x.x, y.x);
        Ct[(4 * q + 1) * 68 + p] = pk2(x.y, y.y);
        Ct[(4 * q + 2) * 68 + p] = pk2(x.z, y.z);
        Ct[(4 * q + 3) * 68 + p] = pk2(x.w, y.w);
    }
    __syncthreads();

    const int l = t & 63;
    const int w = t >> 6;       // wave: d-cols 32w..32w+31
    const int quad = l >> 4;
    const int n16 = l & 15;

    f4v a00 = {0.f, 0.f, 0.f, 0.f}, a01 = a00;
    f4v a10 = a00, a11 = a00, a20 = a00, a21 = a00, a30 = a00, a31 = a00;

#pragma unroll
    for (int ch = 0; ch < 4; ++ch) {
        const int ku = ch * 16 + quad * 4;   // uint col: k = 2*ku..2*ku+7
        const s8v wa0 = *(const s8v*)&Wt[(0  + n16) * 68 + ku];
        const s8v wa1 = *(const s8v*)&Wt[(16 + n16) * 68 + ku];
        const s8v wa2 = *(const s8v*)&Wt[(32 + n16) * 68 + ku];
        const s8v wa3 = *(const s8v*)&Wt[(48 + n16) * 68 + ku];
        const s8v cb0 = *(const s8v*)&Ct[(w * 32 + n16) * 68 + ku];
        const s8v cb1 = *(const s8v*)&Ct[(w * 32 + 16 + n16) * 68 + ku];
        a00 = __builtin_amdgcn_mfma_f32_16x16x32_bf16(wa0, cb0, a00, 0, 0, 0);
        a01 = __builtin_amdgcn_mfma_f32_16x16x32_bf16(wa0, cb1, a01, 0, 0, 0);
        a10 = __builtin_amdgcn_mfma_f32_16x16x32_bf16(wa1, cb0, a10, 0, 0, 0);
        a11 = __builtin_amdgcn_mfma_f32_16x16x32_bf16(wa1, cb1, a11, 0, 0, 0);
        a20 = __builtin_amdgcn_mfma_f32_16x16x32_bf16(wa2, cb0, a20, 0, 0, 0);
        a21 = __builtin_amdgcn_mfma_f32_16x16x32_bf16(wa2, cb1, a21, 0, 0, 0);
        a30 = __builtin_amdgcn_mfma_f32_16x16x32_bf16(wa3, cb0, a30, 0, 0, 0);
        a31 = __builtin_amdgcn_mfma_f32_16x16x32_bf16(wa3, cb1, a31, 0, 0, 0);
    }

    unsigned* __restrict__ up = upk + (size_t)blockIdx.x * (BB * 64);
    const int wi = w * 16 + n16;
#pragma unroll
    for (int r = 0; r < 4; ++r) {
        const int br = quad * 4 + r;
        up[(br +  0) * 64 + wi] = pk2(a00[r], a01[r]);
        up[(br + 16) * 64 + wi] = pk2(a10[r], a11[r]);
        up[(br + 32) * 64 + wi] = pk2(a20[r], a21[r]);
        up[(br + 48) * 64 + wi] = pk2(a30[r], a31[r]);
    }
}

// wave-local Z: sum 2048 per-m partials for b; uniform across the wave
__device__ __forceinline__ float zwave(const float* __restrict__ Zp, int b, int tid) {
    const int lane = tid & 63;
    float z = 0.f;
#pragma unroll
    for (int i = 0; i < 32; ++i)
        z += Zp[(size_t)(lane * 32 + i) * 64 + b];
#pragma unroll
    for (int off = 32; off; off >>= 1) z += __shfl_xor(z, off, 64);
    return z;
}

// ---- reduce hop 0 (prob exact): u += unpacked partial sums ----
__global__ __launch_bounds__(256) void k_reduce_a(const unsigned* __restrict__ upk,
                                                  float* __restrict__ u) {
    const int jc = blockIdx.x & 15;
    const int kc = blockIdx.x >> 4;   // 8 k-chunks of 49
    const int jw = jc * 256 + threadIdx.x;     // 0..4095
    const unsigned* __restrict__ p = upk + (size_t)kc * 49 * (BB * 64) + jw;
    float lo = 0.f, hi = 0.f;
#pragma unroll 7
    for (int k = 0; k < 49; ++k) {
        const unsigned w = p[(size_t)k * (BB * 64)];
        lo += bf2f((unsigned short)w);
        hi += bf2f((unsigned short)(w >> 16));
    }
    const int b = jw >> 6, wi = jw & 63;
    const int d0 = (wi >> 4) * 32 + (wi & 15);
    atomicAdd(u + b * DD + d0, lo);
    atomicAdd(u + b * DD + d0 + 16, hi);
}

// ---- reduce hop 1 (unnormalized W): u += sums * (1/Z[b]) ----
__global__ __launch_bounds__(256) void k_reduce_az(const unsigned* __restrict__ upk,
                                                   const float* __restrict__ Zp,
                                                   float* __restrict__ u) {
    const int jc = blockIdx.x & 15;
    const int kc = blockIdx.x >> 4;
    const int tid = threadIdx.x;
    const int jw = jc * 256 + tid;
    const int b = jw >> 6;            // wave-aligned
    const float rz = 1.f / zwave(Zp, b, tid);
    const unsigned* __restrict__ p = upk + (size_t)kc * 49 * (BB * 64) + jw;
    float lo = 0.f, hi = 0.f;
#pragma unroll 7
    for (int k = 0; k < 49; ++k) {
        const unsigned w = p[(size_t)k * (BB * 64)];
        lo += bf2f((unsigned short)w);
        hi += bf2f((unsigned short)(w >> 16));
    }
    const int wi = jw & 63;
    const int d0 = (wi >> 4) * 32 + (wi & 15);
    atomicAdd(u + b * DD + d0, lo * rz);
    atomicAdd(u + b * DD + d0 + 16, hi * rz);
}

// ---- final reduce hop 2: out = u + sums * (1/Z[b]); 16 blocks owner-computes ----
__global__ __launch_bounds__(256) void k_reduce_finz(const unsigned* __restrict__ upk,
                                                     const float* __restrict__ Zp,
                                                     const float* __restrict__ u,
                                                     float* __restrict__ out) {
    const int tid = threadIdx.x;
    const int jw = blockIdx.x * 256 + tid;   // 0..4095
    const int b = jw >> 6;                   // wave-aligned
    const float rz = 1.f / zwave(Zp, b, tid);
    const unsigned* __restrict__ p = upk + jw;
    float lo = 0.f, hi = 0.f;
#pragma unroll 8
    for (int k = 0; k < NPART; ++k) {
        const unsigned w = p[(size_t)k * (BB * 64)];
        lo += bf2f((unsigned short)w);
        hi += bf2f((unsigned short)(w >> 16));
    }
    const int wi = jw & 63;
    const int d0 = (wi >> 4) * 32 + (wi & 15);
    out[b * DD + d0]      = u[b * DD + d0]      + lo * rz;
    out[b * DD + d0 + 16] = u[b * DD + d0 + 16] + hi * rz;
}

extern "C" void kernel_launch(void* const* d_in, const int* in_sizes, int n_in,
                              void* d_out, int out_size, void* d_ws, size_t ws_size,
                              hipStream_t stream) {
    const int* st = (const int*)d_in[0];
    const float* C = (const float*)d_in[1];

    float* u  = (float*)d_ws;                 // 8192 f, [b][d]
    float* W  = u + BB * DD;                  // VPAD*64 f (scatter target)
    unsigned short* P16 = (unsigned short*)(W + (size_t)VPAD * BB);  // bf16 P
    unsigned* upk = (unsigned*)(P16 + (size_t)VPAD * BB);  // NPART*4096 u32
    float* Zp = (float*)(upk + (size_t)NPART * BB * 64);   // 2048*64 f

    // zero u + W once; W self-cleans each hop via gemm_o writeback
    k_init<<<(BB * DD + VPAD * BB) / 1024, 256, 0, stream>>>((float4*)u);

    // ---- hop 0: prob exactly uniform 1/2048 (u=0) — no GEMM1/attn ----
    k_scatter0<<<(MM * BB * TT) / 256, 256, 0, stream>>>(st, W);
    k_gemm_o<<<VPAD / 128, 256, 0, stream>>>(C + (size_t)1 * VV * DD, W, upk, 1);
    k_reduce_a<<<128, 256, 0, stream>>>(upk, u);

    // ---- hop 1 ----
    k_gemm_p<<<VPAD / 128, 256, 0, stream>>>(C + (size_t)1 * VV * DD, u, P16);
    k_attn2<<<NATT, 256, 0, stream>>>(st, P16, W, Zp);
    k_gemm_o<<<VPAD / 128, 256, 0, stream>>>(C + (size_t)2 * VV * DD, W, upk, 1);
    k_reduce_az<<<128, 256, 0, stream>>>(upk, Zp, u);

    // ---- hop 2 ----
    k_gemm_p<<<VPAD / 128, 256, 0, stream>>>(C + (size_t)2 * VV * DD, u, P16);
    k_attn2<<<NATT, 256, 0, stream>>>(st, P16, W, Zp);
    k_gemm_o<<<VPAD / 128, 256, 0, stream>>>(C + (size_t)3 * VV * DD, W, upk, 0);
    k_reduce_finz<<<16, 256, 0, stream>>>(upk, Zp, u, (float*)d_out);
}

// Round 17
// 312.773 us; speedup vs baseline: 1.0372x; 1.0372x over previous
//
#include <hip/hip_runtime.h>

#define MM 2048     // memory slots
#define BB 64       // batch
#define TT 4        // tokens per slot
#define DD 128      // embed dim
#define VV 50000    // vocab
#define VPAD 50176  // VV rounded up to multiple of 256
#define NPART 392   // gemm_o partial slots (one per block)
#define NATT 512    // attn blocks (Zp partial slots)

typedef float f4v __attribute__((ext_vector_type(4)));
typedef short s8v __attribute__((ext_vector_type(8)));

// float -> bf16 bits (RNE)
__device__ __forceinline__ unsigned short f2bf(float f) {
    unsigned int u = __float_as_uint(f);
    u = u + 0x7FFFu + ((u >> 16) & 1u);
    return (unsigned short)(u >> 16);
}
// bf16 bits -> float
__device__ __forceinline__ float bf2f(unsigned short s) {
    return __uint_as_float((unsigned)s << 16);
}
// pack two floats as bf16 pair
__device__ __forceinline__ unsigned pk2(float lo, float hi) {
    return ((unsigned)f2bf(hi) << 16) | f2bf(lo);
}

// ---- init: zero u (8192 f) and W (VPAD*BB f) — contiguous in workspace ----
__global__ void k_init(float4* __restrict__ p) {
    p[blockIdx.x * 256 + threadIdx.x] = make_float4(0.f, 0.f, 0.f, 0.f);
}

// ---- hop 0 scatter: u=0 -> scores=0 -> prob EXACTLY 1/2048 (uniform). ----
__global__ __launch_bounds__(256) void k_scatter0(const int* __restrict__ st,
                                                  float* __restrict__ W) {
    const int g = blockIdx.x * 256 + threadIdx.x;  // g = m*64+b
    const int b = g & 63;
    const float p = 1.0f / (float)MM;              // exactly representable
    const int4 tk = *(const int4*)(st + (size_t)g * 4);
    if (tk.x) atomicAdd(W + (size_t)tk.x * 64 + b, p);
    if (tk.y) atomicAdd(W + (size_t)tk.y * 64 + b, p);
    if (tk.z) atomicAdd(W + (size_t)tk.z * 64 + b, p);
    if (tk.w) atomicAdd(W + (size_t)tk.w * 64 + b, p);
}

// ---- GEMM1 (MFMA bf16): P[v][b] = dot(C[h][v][:], u[b][:]) ----
// 128 v-rows per block. LDS rows 0..127 = C tile, 128..191 = u.
__global__ __launch_bounds__(256, 3) void k_gemm_p(const float* __restrict__ Ch,
                                                   const float* __restrict__ u,
                                                   float* __restrict__ P) {
    __shared__ short lds[192 * 136];  // 52.2 KB bf16 -> 3 blocks/CU
    const int t = threadIdx.x;
    const int v0 = blockIdx.x * 128;

#pragma unroll
    for (int i = 0; i < 24; ++i) {
        const int G = i * 256 + t;        // f4-index, 6144 total
        const int row = G >> 5;           // 0..191
        const int c4 = G & 31;
        float4 val;
        if (row < 128) {
            const int v = v0 + row;
            val = (v < VV) ? *(const float4*)(Ch + (size_t)v * DD + c4 * 4)
                           : make_float4(0.f, 0.f, 0.f, 0.f);
        } else {
            val = *(const float4*)(u + (size_t)(row - 128) * DD + c4 * 4);
        }
        const unsigned int lo = ((unsigned int)f2bf(val.y) << 16) | f2bf(val.x);
        const unsigned int hi = ((unsigned int)f2bf(val.w) << 16) | f2bf(val.z);
        *(uint2*)(lds + row * 136 + c4 * 4) = make_uint2(lo, hi);
    }
    __syncthreads();

    const int l = t & 63;
    const int w = t >> 6;
    const int quad = l >> 4;
    const int n16 = l & 15;

    const int ar0 = (32 * w + n16) * 136;
    const int ar1 = (32 * w + 16 + n16) * 136;
    const int br0 = (128 + n16) * 136;
    const int br1 = (144 + n16) * 136;
    const int br2 = (160 + n16) * 136;
    const int br3 = (176 + n16) * 136;

    f4v c00 = {0.f, 0.f, 0.f, 0.f}, c01 = c00, c02 = c00, c03 = c00;
    f4v c10 = c00, c11 = c00, c12 = c00, c13 = c00;

#pragma unroll
    for (int s = 0; s < 4; ++s) {
        const int ko = s * 32 + quad * 8;
        const s8v a0 = *(const s8v*)(lds + ar0 + ko);
        const s8v a1 = *(const s8v*)(lds + ar1 + ko);
        const s8v b0 = *(const s8v*)(lds + br0 + ko);
        const s8v b1 = *(const s8v*)(lds + br1 + ko);
        const s8v b2 = *(const s8v*)(lds + br2 + ko);
        const s8v b3 = *(const s8v*)(lds + br3 + ko);
        c00 = __builtin_amdgcn_mfma_f32_16x16x32_bf16(a0, b0, c00, 0, 0, 0);
        c01 = __builtin_amdgcn_mfma_f32_16x16x32_bf16(a0, b1, c01, 0, 0, 0);
        c02 = __builtin_amdgcn_mfma_f32_16x16x32_bf16(a0, b2, c02, 0, 0, 0);
        c03 = __builtin_amdgcn_mfma_f32_16x16x32_bf16(a0, b3, c03, 0, 0, 0);
        c10 = __builtin_amdgcn_mfma_f32_16x16x32_bf16(a1, b0, c10, 0, 0, 0);
        c11 = __builtin_amdgcn_mfma_f32_16x16x32_bf16(a1, b1, c11, 0, 0, 0);
        c12 = __builtin_amdgcn_mfma_f32_16x16x32_bf16(a1, b2, c12, 0, 0, 0);
        c13 = __builtin_amdgcn_mfma_f32_16x16x32_bf16(a1, b3, c13, 0, 0, 0);
    }

    const int vb0 = v0 + 32 * w + quad * 4;
    const int vb1 = vb0 + 16;
#pragma unroll
    for (int r = 0; r < 4; ++r) {
        float* __restrict__ P0 = P + (size_t)(vb0 + r) * 64 + n16;
        P0[0] = c00[r]; P0[16] = c01[r]; P0[32] = c02[r]; P0[48] = c03[r];
        float* __restrict__ P1 = P + (size_t)(vb1 + r) * 64 + n16;
        P1[0] = c10[r]; P1[16] = c11[r]; P1[32] = c12[r]; P1[48] = c13[r];
    }
}

// ---- attention, m-parallel: scatter UNNORMALIZED e^s; Zp[bid][b] partials ----
__global__ __launch_bounds__(256) void k_attn2(const int* __restrict__ st,
                                               const float* __restrict__ P,
                                               float* __restrict__ W,
                                               float* __restrict__ Zp) {
    __shared__ float eb[256];
    const int tid = threadIdx.x;
    const int g = blockIdx.x * 256 + tid;  // g = m*64+b
    const int b = g & 63;

    const int4 tk = *(const int4*)(st + (size_t)g * 4);  // coalesced
    float s = 0.f;
    if (tk.x) s += P[(size_t)tk.x * 64 + b];
    if (tk.y) s += P[(size_t)tk.y * 64 + b];
    if (tk.z) s += P[(size_t)tk.z * 64 + b];
    if (tk.w) s += P[(size_t)tk.w * 64 + b];
    const float e = __expf(s);
    eb[tid] = e;

    if (tk.x) atomicAdd(W + (size_t)tk.x * 64 + b, e);
    if (tk.y) atomicAdd(W + (size_t)tk.y * 64 + b, e);
    if (tk.z) atomicAdd(W + (size_t)tk.z * 64 + b, e);
    if (tk.w) atomicAdd(W + (size_t)tk.w * 64 + b, e);

    __syncthreads();
    if (tid < 64)  // lane tid == b of the block's 4 m-rows; no atomics
        Zp[(size_t)blockIdx.x * 64 + tid] =
            (eb[tid] + eb[tid + 64]) + (eb[tid + 128] + eb[tid + 192]);
}

// ---- GEMM2 (MFMA bf16): partials PACKED bf16x2 -> upk[part][b][wi] ----
// word wi = w*16+n16 holds (d0, d0+16) where d0 = (wi>>4)*32 + (wi&15).
__global__ __launch_bounds__(256, 3) void k_gemm_o(const float* __restrict__ C2,
                                                   float* __restrict__ W,
                                                   unsigned* __restrict__ upk,
                                                   const int rezero) {
    __shared__ unsigned Wt[64 * 68];    // 17.4 KB [b][v-pair]
    __shared__ unsigned Ct[128 * 68];   // 34.8 KB [d][v-pair]
    const int t = threadIdx.x;
    const int vb = blockIdx.x * 128;

#pragma unroll
    for (int i = 0; i < 4; ++i) {
        const int item = i * 256 + t;
        const int q = item & 15;          // b-quad
        const int p = item >> 4;          // v-pair 0..63
        float* w0 = W + (size_t)(vb + 2 * p) * 64 + 4 * q;
        float* w1 = W + (size_t)(vb + 2 * p + 1) * 64 + 4 * q;
        const float4 x = *(const float4*)w0;
        const float4 y = *(const float4*)w1;
        if (rezero) {
            *(float4*)w0 = make_float4(0.f, 0.f, 0.f, 0.f);
            *(float4*)w1 = make_float4(0.f, 0.f, 0.f, 0.f);
        }
        Wt[(4 * q + 0) * 68 + p] = pk2(x.x, y.x);
        Wt[(4 * q + 1) * 68 + p] = pk2(x.y, y.y);
        Wt[(4 * q + 2) * 68 + p] = pk2(x.z, y.z);
        Wt[(4 * q + 3) * 68 + p] = pk2(x.w, y.w);
    }
#pragma unroll
    for (int i = 0; i < 8; ++i) {
        const int item = i * 256 + t;
        const int q = item & 31;          // d-quad
        const int p = item >> 5;          // v-pair 0..63
        const int v0 = vb + 2 * p;
        const float4 x = (v0 < VV)
            ? *(const float4*)(C2 + (size_t)v0 * DD + 4 * q)
            : make_float4(0.f, 0.f, 0.f, 0.f);
        const float4 y = (v0 + 1 < VV)
            ? *(const float4*)(C2 + (size_t)(v0 + 1) * DD + 4 * q)
            : make_float4(0.f, 0.f, 0.f, 0.f);
        Ct[(4 * q + 0) * 68 + p] = pk2(x.x, y.x);
        Ct[(4 * q + 1) * 68 + p] = pk2(x.y, y.y);
        Ct[(4 * q + 2) * 68 + p] = pk2(x.z, y.z);
        Ct[(4 * q + 3) * 68 + p] = pk2(x.w, y.w);
    }
    __syncthreads();

    const int l = t & 63;
    const int w = t >> 6;       // wave: d-cols 32w..32w+31
    const int quad = l >> 4;
    const int n16 = l & 15;

    f4v a00 = {0.f, 0.f, 0.f, 0.f}, a01 = a00;
    f4v a10 = a00, a11 = a00, a20 = a00, a21 = a00, a30 = a00, a31 = a00;

#pragma unroll
    for (int ch = 0; ch < 4; ++ch) {
        const int ku = ch * 16 + quad * 4;   // uint col: k = 2*ku..2*ku+7
        const s8v wa0 = *(const s8v*)&Wt[(0  + n16) * 68 + ku];
        const s8v wa1 = *(const s8v*)&Wt[(16 + n16) * 68 + ku];
        const s8v wa2 = *(const s8v*)&Wt[(32 + n16) * 68 + ku];
        const s8v wa3 = *(const s8v*)&Wt[(48 + n16) * 68 + ku];
        const s8v cb0 = *(const s8v*)&Ct[(w * 32 + n16) * 68 + ku];
        const s8v cb1 = *(const s8v*)&Ct[(w * 32 + 16 + n16) * 68 + ku];
        a00 = __builtin_amdgcn_mfma_f32_16x16x32_bf16(wa0, cb0, a00, 0, 0, 0);
        a01 = __builtin_amdgcn_mfma_f32_16x16x32_bf16(wa0, cb1, a01, 0, 0, 0);
        a10 = __builtin_amdgcn_mfma_f32_16x16x32_bf16(wa1, cb0, a10, 0, 0, 0);
        a11 = __builtin_amdgcn_mfma_f32_16x16x32_bf16(wa1, cb1, a11, 0, 0, 0);
        a20 = __builtin_amdgcn_mfma_f32_16x16x32_bf16(wa2, cb0, a20, 0, 0, 0);
        a21 = __builtin_amdgcn_mfma_f32_16x16x32_bf16(wa2, cb1, a21, 0, 0, 0);
        a30 = __builtin_amdgcn_mfma_f32_16x16x32_bf16(wa3, cb0, a30, 0, 0, 0);
        a31 = __builtin_amdgcn_mfma_f32_16x16x32_bf16(wa3, cb1, a31, 0, 0, 0);
    }

    // pack (d0, d0+16) pairs as bf16x2: halves partial traffic both ways
    unsigned* __restrict__ up = upk + (size_t)blockIdx.x * (BB * 64);
    const int wi = w * 16 + n16;
#pragma unroll
    for (int r = 0; r < 4; ++r) {
        const int br = quad * 4 + r;
        up[(br +  0) * 64 + wi] = pk2(a00[r], a01[r]);
        up[(br + 16) * 64 + wi] = pk2(a10[r], a11[r]);
        up[(br + 32) * 64 + wi] = pk2(a20[r], a21[r]);
        up[(br + 48) * 64 + wi] = pk2(a30[r], a31[r]);
    }
}

// wave-local Z: wave w of this block owns b = b_base + w (matches jw>>6)
__device__ __forceinline__ float zwave(const float* __restrict__ Zp, int b, int tid) {
    const int lane = tid & 63;
    float z = 0.f;
#pragma unroll
    for (int i = 0; i < 8; ++i)
        z += Zp[(size_t)(lane * 8 + i) * 64 + b];
#pragma unroll
    for (int off = 32; off; off >>= 1) z += __shfl_xor(z, off, 64);
    return z;   // uniform across the wave
}

// ---- reduce hop 0 (prob exact): u += unpacked partial sums ----
// 128 blocks (16 jc x 8 kc); word jw -> b=jw>>6, wi=jw&63, d0/(d0+16).
__global__ __launch_bounds__(256) void k_reduce_a(const unsigned* __restrict__ upk,
                                                  float* __restrict__ u) {
    const int jc = blockIdx.x & 15;
    const int kc = blockIdx.x >> 4;   // 8 k-chunks of 49
    const int jw = jc * 256 + threadIdx.x;     // 0..4095
    const unsigned* __restrict__ p = upk + (size_t)kc * 49 * (BB * 64) + jw;
    float lo = 0.f, hi = 0.f;
#pragma unroll 7
    for (int k = 0; k < 49; ++k) {
        const unsigned w = p[(size_t)k * (BB * 64)];
        lo += bf2f((unsigned short)w);
        hi += bf2f((unsigned short)(w >> 16));
    }
    const int b = jw >> 6, wi = jw & 63;
    const int d0 = (wi >> 4) * 32 + (wi & 15);
    atomicAdd(u + b * DD + d0, lo);
    atomicAdd(u + b * DD + d0 + 16, hi);
}

// ---- reduce hop 1 (unnormalized W): u += sums * (1/Z[b]) ----
__global__ __launch_bounds__(256) void k_reduce_az(const unsigned* __restrict__ upk,
                                                   const float* __restrict__ Zp,
                                                   float* __restrict__ u) {
    const int jc = blockIdx.x & 15;
    const int kc = blockIdx.x >> 4;
    const int tid = threadIdx.x;
    const int jw = jc * 256 + tid;
    const int b = jw >> 6;            // = jc*4 + (tid>>6): wave-aligned
    const float rz = 1.f / zwave(Zp, b, tid);
    const unsigned* __restrict__ p = upk + (size_t)kc * 49 * (BB * 64) + jw;
    float lo = 0.f, hi = 0.f;
#pragma unroll 7
    for (int k = 0; k < 49; ++k) {
        const unsigned w = p[(size_t)k * (BB * 64)];
        lo += bf2f((unsigned short)w);
        hi += bf2f((unsigned short)(w >> 16));
    }
    const int wi = jw & 63;
    const int d0 = (wi >> 4) * 32 + (wi & 15);
    atomicAdd(u + b * DD + d0, lo * rz);
    atomicAdd(u + b * DD + d0 + 16, hi * rz);
}

// ---- final reduce hop 2: out = u + sums * (1/Z[b]); 16 blocks owner-computes ----
__global__ __launch_bounds__(256) void k_reduce_finz(const unsigned* __restrict__ upk,
                                                     const float* __restrict__ Zp,
                                                     const float* __restrict__ u,
                                                     float* __restrict__ out) {
    const int tid = threadIdx.x;
    const int jw = blockIdx.x * 256 + tid;   // 0..4095
    const int b = jw >> 6;                   // wave-aligned
    const float rz = 1.f / zwave(Zp, b, tid);
    const unsigned* __restrict__ p = upk + jw;
    float lo = 0.f, hi = 0.f;
#pragma unroll 8
    for (int k = 0; k < NPART; ++k) {
        const unsigned w = p[(size_t)k * (BB * 64)];
        lo += bf2f((unsigned short)w);
        hi += bf2f((unsigned short)(w >> 16));
    }
    const int wi = jw & 63;
    const int d0 = (wi >> 4) * 32 + (wi & 15);
    out[b * DD + d0]      = u[b * DD + d0]      + lo * rz;
    out[b * DD + d0 + 16] = u[b * DD + d0 + 16] + hi * rz;
}

extern "C" void kernel_launch(void* const* d_in, const int* in_sizes, int n_in,
                              void* d_out, int out_size, void* d_ws, size_t ws_size,
                              hipStream_t stream) {
    const int* st = (const int*)d_in[0];
    const float* C = (const float*)d_in[1];

    float* u  = (float*)d_ws;                 // 8192 f, [b][d]
    float* W  = u + BB * DD;                  // VPAD*64 f (scatter target)
    float* P  = W + (size_t)VPAD * BB;        // VPAD*64 f (GEMM1 output)
    unsigned* upk = (unsigned*)(P + (size_t)VPAD * BB);  // NPART*4096 u32
    float* Zp = (float*)(upk + (size_t)NPART * BB * 64); // 512*64 f

    // zero u + W once; W self-cleans each hop via gemm_o writeback
    k_init<<<(BB * DD + VPAD * BB) / 1024, 256, 0, stream>>>((float4*)u);

    // ---- hop 0: prob exactly uniform 1/2048 (u=0) — no GEMM1/attn ----
    k_scatter0<<<(MM * BB) / 256, 256, 0, stream>>>(st, W);
    k_gemm_o<<<VPAD / 128, 256, 0, stream>>>(C + (size_t)1 * VV * DD, W, upk, 1);
    k_reduce_a<<<128, 256, 0, stream>>>(upk, u);

    // ---- hop 1 ----
    k_gemm_p<<<VPAD / 128, 256, 0, stream>>>(C + (size_t)1 * VV * DD, u, P);
    k_attn2<<<NATT, 256, 0, stream>>>(st, P, W, Zp);
    k_gemm_o<<<VPAD / 128, 256, 0, stream>>>(C + (size_t)2 * VV * DD, W, upk, 1);
    k_reduce_az<<<128, 256, 0, stream>>>(upk, Zp, u);

    // ---- hop 2 ----
    k_gemm_p<<<VPAD / 128, 256, 0, stream>>>(C + (size_t)2 * VV * DD, u, P);
    k_attn2<<<NATT, 256, 0, stream>>>(st, P, W, Zp);
    k_gemm_o<<<VPAD / 128, 256, 0, stream>>>(C + (size_t)3 * VV * DD, W, upk, 0);
    k_reduce_finz<<<16, 256, 0, stream>>>(upk, Zp, u, (float*)d_out);
}